// Round 9
// baseline (344.664 us; speedup 1.0000x reference)
//
#include <hip/hip_runtime.h>

#define N_NODES 100000
#define N_EDGES 1600000
#define RSHIFT 8
#define RSIZE 256
#define NREG 391            // cdiv(100000, 256)
#define CAP 8192            // staging slots per region (expected ~4096, sd ~64)
#define CH 2048             // edges per workgroup in place pass
#define NWG_E 782           // cdiv(N_EDGES, CH)
#define S1 5                // LDS acc stride layer1 (odd -> conflict-free-ish)
#define S2 17               // layer2
#define S3 9                // layer3

static inline int cdiv(int a, int b) { return (a + b - 1) / b; }

__device__ inline float4 f4fma(float s, float4 w, float4 a) {
    a.x = fmaf(s, w.x, a.x); a.y = fmaf(s, w.y, a.y);
    a.z = fmaf(s, w.z, a.z); a.w = fmaf(s, w.w, a.w); return a;
}

// ---------------- CSR-lite build: single-pass region partition ----------------

__global__ void k_zero_cur(int* __restrict__ p) {
    int i = blockIdx.x * blockDim.x + threadIdx.x;
    if (i < NREG) p[i] = 0;
}

// LDS hist chunk -> reserve window slice -> re-read chunk (L2-hot) and place
__global__ __launch_bounds__(256) void k_place(const int* __restrict__ src,
                                               const int* __restrict__ dst,
                                               int* __restrict__ regionCursor,
                                               unsigned* __restrict__ staging) {
    __shared__ int h[NREG];
    __shared__ int cur[NREG];
    int wg = blockIdx.x;
    for (int t = threadIdx.x; t < NREG; t += 256) h[t] = 0;
    __syncthreads();
    int e0 = wg * CH;
    int e1 = e0 + CH; if (e1 > N_EDGES) e1 = N_EDGES;
    const int4* s4 = (const int4*)src;
    const int4* d4 = (const int4*)dst;
    for (int k = e0 / 4 + threadIdx.x; k < e1 / 4; k += 256) {
        int4 d = d4[k];
        atomicAdd(&h[d.x >> RSHIFT], 1);
        atomicAdd(&h[d.y >> RSHIFT], 1);
        atomicAdd(&h[d.z >> RSHIFT], 1);
        atomicAdd(&h[d.w >> RSHIFT], 1);
    }
    __syncthreads();
    for (int t = threadIdx.x; t < NREG; t += 256)
        cur[t] = t * CAP + atomicAdd(&regionCursor[t], h[t]);
    __syncthreads();
    for (int k = e0 / 4 + threadIdx.x; k < e1 / 4; k += 256) {
        int4 s = s4[k];
        int4 d = d4[k];
        int p;
        p = atomicAdd(&cur[d.x >> RSHIFT], 1); staging[p] = ((unsigned)(d.x & (RSIZE - 1)) << 17) | (unsigned)s.x;
        p = atomicAdd(&cur[d.y >> RSHIFT], 1); staging[p] = ((unsigned)(d.y & (RSIZE - 1)) << 17) | (unsigned)s.y;
        p = atomicAdd(&cur[d.z >> RSHIFT], 1); staging[p] = ((unsigned)(d.z & (RSIZE - 1)) << 17) | (unsigned)s.z;
        p = atomicAdd(&cur[d.w >> RSHIFT], 1); staging[p] = ((unsigned)(d.w & (RSIZE - 1)) << 17) | (unsigned)s.w;
    }
}

// per-region degree histogram -> dinv, xd = {x*dinv, 0}
__global__ __launch_bounds__(512) void k_deg(const unsigned* __restrict__ staging,
                                             const int* __restrict__ regionCursor,
                                             const float* __restrict__ x,
                                             float* __restrict__ dinv,
                                             float4* __restrict__ xd) {
    __shared__ int cnt[RSIZE];
    int r = blockIdx.x, t = threadIdx.x;
    if (t < RSIZE) cnt[t] = 0;
    __syncthreads();
    int e0 = r * CAP, e1v = e0 + regionCursor[r];
    for (int k = e0 + t; k < e1v; k += 512) atomicAdd(&cnt[staging[k] >> 17], 1);
    __syncthreads();
    int i = (r << RSHIFT) + t;
    if (t < RSIZE && i < N_NODES) {
        float di = rsqrtf((float)(cnt[t] + 1));
        dinv[i] = di;
        float4 v;
        v.x = x[3 * i] * di; v.y = x[3 * i + 1] * di; v.z = x[3 * i + 2] * di; v.w = 0.0f;
        xd[i] = v;
    }
}

// ---------------- edge-parallel fused layers (LDS accumulators) ----------------

// layer 1: agg xd (3ch) edge-parallel + transform 3->32 + relu + 32->16, write h2n*dinv
__global__ __launch_bounds__(512) void e1(const unsigned* __restrict__ staging,
                                          const int* __restrict__ regionCursor,
                                          const float4* __restrict__ xd,
                                          const float* __restrict__ dinv,
                                          const float* __restrict__ b1,
                                          const float* __restrict__ W1,
                                          const float* __restrict__ W2,
                                          float4* __restrict__ h2n) {
    __shared__ float acc[RSIZE * S1];
    __shared__ float4 sW1[24];    // [3][32] as 3 rows x 8 quads
    __shared__ float4 sW2[128];   // [32][16] as 32 rows x 4 quads
    int r = blockIdx.x, t = threadIdx.x;
    int base = r << RSHIFT;
    if (t < 24) sW1[t] = ((const float4*)W1)[t];
    if (t >= 24 && t < 152) sW2[t - 24] = ((const float4*)W2)[t - 24];
    if (t < RSIZE) {
        int i = base + t;
        float4 v = {0, 0, 0, 0};
        if (i < N_NODES) v = xd[i];            // self loop
        acc[t * S1 + 0] = v.x; acc[t * S1 + 1] = v.y; acc[t * S1 + 2] = v.z;
    }
    __syncthreads();
    int e0 = r * CAP, e1v = e0 + regionCursor[r];
    for (int k = e0 + t; k < e1v; k += 512) {
        unsigned p = staging[k];
        float4 v = xd[p & 0x1FFFFu];
        int o = (int)(p >> 17) * S1;
        atomicAdd(&acc[o + 0], v.x);
        atomicAdd(&acc[o + 1], v.y);
        atomicAdd(&acc[o + 2], v.z);           // .w is always 0
    }
    __syncthreads();
    int i = base + t;
    if (t < RSIZE && i < N_NODES) {
        float ax = acc[t * S1], ay = acc[t * S1 + 1], az = acc[t * S1 + 2];
        float di = dinv[i];
        const float4* b14 = (const float4*)b1;
        float h[32];
#pragma unroll
        for (int q = 0; q < 8; ++q) {
            float4 s = {0, 0, 0, 0};
            s = f4fma(ax, sW1[q], s);
            s = f4fma(ay, sW1[8 + q], s);
            s = f4fma(az, sW1[16 + q], s);
            float4 bb = b14[q];
            h[4 * q]     = fmaxf(fmaf(di, s.x, bb.x), 0.0f);
            h[4 * q + 1] = fmaxf(fmaf(di, s.y, bb.y), 0.0f);
            h[4 * q + 2] = fmaxf(fmaf(di, s.z, bb.z), 0.0f);
            h[4 * q + 3] = fmaxf(fmaf(di, s.w, bb.w), 0.0f);
        }
        float4 o[4] = {{0,0,0,0},{0,0,0,0},{0,0,0,0},{0,0,0,0}};
#pragma unroll
        for (int k = 0; k < 32; ++k) {
            float hk = h[k];
#pragma unroll
            for (int q = 0; q < 4; ++q) o[q] = f4fma(hk, sW2[k * 4 + q], o[q]);
        }
#pragma unroll
        for (int q = 0; q < 4; ++q) {
            o[q].x *= di; o[q].y *= di; o[q].z *= di; o[q].w *= di;
            h2n[(size_t)i * 4 + q] = o[q];
        }
    }
}

// layer 2: agg h2n (16ch) edge-parallel + relu + transform 16->8, write h3n*dinv
__global__ __launch_bounds__(512) void e2(const unsigned* __restrict__ staging,
                                          const int* __restrict__ regionCursor,
                                          const float4* __restrict__ h2n,
                                          const float* __restrict__ dinv,
                                          const float* __restrict__ b2,
                                          const float* __restrict__ W3,
                                          float4* __restrict__ h3n) {
    __shared__ float acc[RSIZE * S2];   // 17.4 KB
    __shared__ float4 sW3[32];          // [16][8] as 16 rows x 2 quads
    int r = blockIdx.x, t = threadIdx.x;
    int base = r << RSHIFT;
    if (t < 32) sW3[t] = ((const float4*)W3)[t];
    if (t < RSIZE) {
        int i = base + t;
#pragma unroll
        for (int q = 0; q < 4; ++q) {
            float4 v = {0, 0, 0, 0};
            if (i < N_NODES) v = h2n[(size_t)i * 4 + q];   // self loop
            acc[t * S2 + 4 * q]     = v.x;
            acc[t * S2 + 4 * q + 1] = v.y;
            acc[t * S2 + 4 * q + 2] = v.z;
            acc[t * S2 + 4 * q + 3] = v.w;
        }
    }
    __syncthreads();
    int e0 = r * CAP, e1v = e0 + regionCursor[r];
    for (int k = e0 + t; k < e1v; k += 512) {
        unsigned p = staging[k];
        const float4* hp = &h2n[(size_t)(p & 0x1FFFFu) * 4];
        float4 a0 = hp[0], a1 = hp[1], a2 = hp[2], a3 = hp[3];
        int o = (int)(p >> 17) * S2;
        atomicAdd(&acc[o + 0],  a0.x); atomicAdd(&acc[o + 1],  a0.y);
        atomicAdd(&acc[o + 2],  a0.z); atomicAdd(&acc[o + 3],  a0.w);
        atomicAdd(&acc[o + 4],  a1.x); atomicAdd(&acc[o + 5],  a1.y);
        atomicAdd(&acc[o + 6],  a1.z); atomicAdd(&acc[o + 7],  a1.w);
        atomicAdd(&acc[o + 8],  a2.x); atomicAdd(&acc[o + 9],  a2.y);
        atomicAdd(&acc[o + 10], a2.z); atomicAdd(&acc[o + 11], a2.w);
        atomicAdd(&acc[o + 12], a3.x); atomicAdd(&acc[o + 13], a3.y);
        atomicAdd(&acc[o + 14], a3.z); atomicAdd(&acc[o + 15], a3.w);
    }
    __syncthreads();
    int i = base + t;
    if (t < RSIZE && i < N_NODES) {
        float di = dinv[i];
        float act[16];
#pragma unroll
        for (int c = 0; c < 16; ++c)
            act[c] = fmaxf(fmaf(di, acc[t * S2 + c], b2[c]), 0.0f);
        float4 o0 = {0,0,0,0}, o1 = {0,0,0,0};
#pragma unroll
        for (int k = 0; k < 16; ++k) {
            o0 = f4fma(act[k], sW3[k * 2], o0);
            o1 = f4fma(act[k], sW3[k * 2 + 1], o1);
        }
        o0.x *= di; o0.y *= di; o0.z *= di; o0.w *= di;
        o1.x *= di; o1.y *= di; o1.z *= di; o1.w *= di;
        h3n[(size_t)i * 2]     = o0;
        h3n[(size_t)i * 2 + 1] = o1;
    }
}

// layer 3: agg h3n (8ch) edge-parallel + relu + final 8->1 linear
__global__ __launch_bounds__(512) void e3(const unsigned* __restrict__ staging,
                                          const int* __restrict__ regionCursor,
                                          const float4* __restrict__ h3n,
                                          const float* __restrict__ dinv,
                                          const float* __restrict__ b3,
                                          const float* __restrict__ Wf,
                                          const float* __restrict__ bf,
                                          float* __restrict__ out) {
    __shared__ float acc[RSIZE * S3];   // 9.2 KB
    int r = blockIdx.x, t = threadIdx.x;
    int base = r << RSHIFT;
    if (t < RSIZE) {
        int i = base + t;
#pragma unroll
        for (int q = 0; q < 2; ++q) {
            float4 v = {0, 0, 0, 0};
            if (i < N_NODES) v = h3n[(size_t)i * 2 + q];   // self loop
            acc[t * S3 + 4 * q]     = v.x;
            acc[t * S3 + 4 * q + 1] = v.y;
            acc[t * S3 + 4 * q + 2] = v.z;
            acc[t * S3 + 4 * q + 3] = v.w;
        }
    }
    __syncthreads();
    int e0 = r * CAP, e1v = e0 + regionCursor[r];
    for (int k = e0 + t; k < e1v; k += 512) {
        unsigned p = staging[k];
        const float4* hp = &h3n[(size_t)(p & 0x1FFFFu) * 2];
        float4 a0 = hp[0], a1 = hp[1];
        int o = (int)(p >> 17) * S3;
        atomicAdd(&acc[o + 0], a0.x); atomicAdd(&acc[o + 1], a0.y);
        atomicAdd(&acc[o + 2], a0.z); atomicAdd(&acc[o + 3], a0.w);
        atomicAdd(&acc[o + 4], a1.x); atomicAdd(&acc[o + 5], a1.y);
        atomicAdd(&acc[o + 6], a1.z); atomicAdd(&acc[o + 7], a1.w);
    }
    __syncthreads();
    int i = base + t;
    if (t < RSIZE && i < N_NODES) {
        float di = dinv[i];
        float s = bf[0];
#pragma unroll
        for (int c = 0; c < 8; ++c)
            s = fmaf(fmaxf(fmaf(di, acc[t * S3 + c], b3[c]), 0.0f), Wf[c], s);
        out[i] = s;
    }
}

// ---------------- launch ----------------

extern "C" void kernel_launch(void* const* d_in, const int* in_sizes, int n_in,
                              void* d_out, int out_size, void* d_ws, size_t ws_size,
                              hipStream_t stream) {
    const float* x  = (const float*)d_in[0];
    const int*   ei = (const int*)d_in[1];
    const float* W1 = (const float*)d_in[2];
    const float* b1 = (const float*)d_in[3];
    const float* W2 = (const float*)d_in[4];
    const float* b2 = (const float*)d_in[5];
    const float* W3 = (const float*)d_in[6];
    const float* b3 = (const float*)d_in[7];
    const float* Wf = (const float*)d_in[8];
    const float* bf = (const float*)d_in[9];
    float* out = (float*)d_out;

    const int n = N_NODES;
    const int e = N_EDGES;
    const int* src = ei;
    const int* dst = ei + e;

    // workspace: xd[n]f4 | h2n[n*4]f4 | h3n[n*2]f4 | dinv[n] | staging[NREG*CAP]u32 | regionCursor[NREG]
    float4*   xd   = (float4*)d_ws;
    float4*   h2n  = xd + n;
    float4*   h3n  = h2n + (size_t)n * 4;
    float*    dinv = (float*)(h3n + (size_t)n * 2);
    unsigned* staging = (unsigned*)(dinv + n);
    int*      regionCursor = (int*)(staging + (size_t)NREG * CAP);

    // ---- region partition ----
    k_zero_cur<<<2, 256, 0, stream>>>(regionCursor);
    k_place<<<NWG_E, 256, 0, stream>>>(src, dst, regionCursor, staging);
    k_deg<<<NREG, 512, 0, stream>>>(staging, regionCursor, x, dinv, xd);

    // ---- edge-parallel fused layers ----
    e1<<<NREG, 512, 0, stream>>>(staging, regionCursor, xd, dinv, b1, W1, W2, h2n);
    e2<<<NREG, 512, 0, stream>>>(staging, regionCursor, h2n, dinv, b2, W3, h3n);
    e3<<<NREG, 512, 0, stream>>>(staging, regionCursor, h3n, dinv, b3, Wf, bf, out);
}

// Round 10
// 109.799 us; speedup vs baseline: 3.1391x; 3.1391x over previous
//
#include <hip/hip_runtime.h>

#define N_NODES 100000
#define N_EDGES 1600000
#define RSHIFT 9
#define RSIZE 512
#define NREG 196            // cdiv(100000, 512)
#define CAP 16384           // staging slots per region (expected 8192, sd ~90)
#define CH 2048             // edges per workgroup in place pass
#define NWG_E 782           // cdiv(N_EDGES, CH)
#define NPB 64              // nodes per block in gather kernels

static inline int cdiv(int a, int b) { return (a + b - 1) / b; }

__device__ inline float4 f4fma(float s, float4 w, float4 a) {
    a.x = fmaf(s, w.x, a.x); a.y = fmaf(s, w.y, a.y);
    a.z = fmaf(s, w.z, a.z); a.w = fmaf(s, w.w, a.w); return a;
}

// ---------------- CSR build: single-pass place + per-region build (round-8, known good) ----------------

__global__ void k_zero_cur(int* __restrict__ p) {
    int i = threadIdx.x;
    if (i < NREG) p[i] = 0;
}

__global__ __launch_bounds__(256) void k_place(const int* __restrict__ src,
                                               const int* __restrict__ dst,
                                               int* __restrict__ regionCursor,
                                               unsigned* __restrict__ staging) {
    __shared__ int h[NREG];
    __shared__ int cur[NREG];
    int wg = blockIdx.x;
    for (int t = threadIdx.x; t < NREG; t += 256) h[t] = 0;
    __syncthreads();
    int e0 = wg * CH;
    int e1 = e0 + CH; if (e1 > N_EDGES) e1 = N_EDGES;
    const int4* s4 = (const int4*)src;
    const int4* d4 = (const int4*)dst;
    for (int k = e0 / 4 + threadIdx.x; k < e1 / 4; k += 256) {
        int4 d = d4[k];
        atomicAdd(&h[d.x >> RSHIFT], 1);
        atomicAdd(&h[d.y >> RSHIFT], 1);
        atomicAdd(&h[d.z >> RSHIFT], 1);
        atomicAdd(&h[d.w >> RSHIFT], 1);
    }
    __syncthreads();
    for (int t = threadIdx.x; t < NREG; t += 256)
        cur[t] = t * CAP + atomicAdd(&regionCursor[t], h[t]);
    __syncthreads();
    for (int k = e0 / 4 + threadIdx.x; k < e1 / 4; k += 256) {
        int4 s = s4[k];
        int4 d = d4[k];
        int p;
        p = atomicAdd(&cur[d.x >> RSHIFT], 1); staging[p] = ((unsigned)(d.x & (RSIZE - 1)) << 17) | (unsigned)s.x;
        p = atomicAdd(&cur[d.y >> RSHIFT], 1); staging[p] = ((unsigned)(d.y & (RSIZE - 1)) << 17) | (unsigned)s.y;
        p = atomicAdd(&cur[d.z >> RSHIFT], 1); staging[p] = ((unsigned)(d.z & (RSIZE - 1)) << 17) | (unsigned)s.z;
        p = atomicAdd(&cur[d.w >> RSHIFT], 1); staging[p] = ((unsigned)(d.w & (RSIZE - 1)) << 17) | (unsigned)s.w;
    }
}

__global__ __launch_bounds__(512) void k_build(const unsigned* __restrict__ staging,
                                               const int* __restrict__ regionCursor,
                                               const float* __restrict__ x,
                                               int* __restrict__ rowptr,
                                               int* __restrict__ rowend,
                                               float* __restrict__ dinv,
                                               float4* __restrict__ xd,
                                               int* __restrict__ srcs) {
    __shared__ int cnt[RSIZE];
    __shared__ int scn[RSIZE];
    int r = blockIdx.x;
    int t = threadIdx.x;
    int base = r << RSHIFT;
    int nloc = N_NODES - base; if (nloc > RSIZE) nloc = RSIZE;
    int e0 = r * CAP;
    int e1 = e0 + regionCursor[r];
    cnt[t] = 0;
    __syncthreads();
    for (int k = e0 + t; k < e1; k += 512) atomicAdd(&cnt[staging[k] >> 17], 1);
    __syncthreads();
    int v = cnt[t];
    scn[t] = v;
    __syncthreads();
    for (int off = 1; off < RSIZE; off <<= 1) {
        int y = (t >= off) ? scn[t - off] : 0;
        __syncthreads();
        scn[t] += y;
        __syncthreads();
    }
    int excl = scn[t] - v;
    if (t < nloc) {
        int i = base + t;
        rowptr[i] = e0 + excl;
        rowend[i] = e0 + excl + v;
        float di = rsqrtf((float)(v + 1));
        dinv[i] = di;
        float4 vv;
        vv.x = x[3 * i] * di; vv.y = x[3 * i + 1] * di; vv.z = x[3 * i + 2] * di; vv.w = 0.0f;
        xd[i] = vv;
    }
    cnt[t] = e0 + excl;   // reuse as cursor
    __syncthreads();
    for (int k = e0 + t; k < e1; k += 512) {
        unsigned p = staging[k];
        int pos = atomicAdd(&cnt[p >> 17], 1);
        srcs[pos] = (int)(p & 0x1FFFFu);
    }
}

// ---------------- fused layers: 4 threads/node gather + LDS exchange ----------------

// layer 1: 4-way EDGE-split aggregate of xd (4ch) + 3->32 relu + 32->16, write h2n*dinv
__global__ __launch_bounds__(256) void g1(const int* __restrict__ rowptr,
                                          const int* __restrict__ rowend,
                                          const int* __restrict__ srcs,
                                          const float4* __restrict__ xd,
                                          const float* __restrict__ dinv,
                                          const float* __restrict__ b1,
                                          const float* __restrict__ W1,
                                          const float* __restrict__ W2,
                                          float4* __restrict__ h2n) {
    __shared__ float4 sAcc[NPB][4];
    __shared__ float4 sW1[24];    // [3][32] as 3 rows x 8 quads
    __shared__ float4 sW2[128];   // [32][16] as 32 rows x 4 quads
    int t = threadIdx.x;
    if (t < 24) sW1[t] = ((const float4*)W1)[t];
    if (t >= 24 && t < 152) sW2[t - 24] = ((const float4*)W2)[t - 24];
    int nl = t >> 2, q = t & 3;
    int i = blockIdx.x * NPB + nl;
    float4 acc = {0, 0, 0, 0};
    if (i < N_NODES) {
        if (q == 0) acc = xd[i];              // self loop
        int r0 = rowptr[i], r1 = rowend[i];
        for (int j = r0 + q; j < r1; j += 4) {
            float4 v = xd[srcs[j]];
            acc.x += v.x; acc.y += v.y; acc.z += v.z;
        }
    }
    sAcc[nl][q] = acc;
    __syncthreads();
    if (t < NPB) {
        int ii = blockIdx.x * NPB + t;
        if (ii < N_NODES) {
            float4 p0 = sAcc[t][0], p1 = sAcc[t][1], p2 = sAcc[t][2], p3 = sAcc[t][3];
            float ax = p0.x + p1.x + p2.x + p3.x;
            float ay = p0.y + p1.y + p2.y + p3.y;
            float az = p0.z + p1.z + p2.z + p3.z;
            float di = dinv[ii];
            const float4* b14 = (const float4*)b1;
            float h[32];
#pragma unroll
            for (int qq = 0; qq < 8; ++qq) {
                float4 s = {0, 0, 0, 0};
                s = f4fma(ax, sW1[qq], s);
                s = f4fma(ay, sW1[8 + qq], s);
                s = f4fma(az, sW1[16 + qq], s);
                float4 bb = b14[qq];
                h[4 * qq]     = fmaxf(fmaf(di, s.x, bb.x), 0.0f);
                h[4 * qq + 1] = fmaxf(fmaf(di, s.y, bb.y), 0.0f);
                h[4 * qq + 2] = fmaxf(fmaf(di, s.z, bb.z), 0.0f);
                h[4 * qq + 3] = fmaxf(fmaf(di, s.w, bb.w), 0.0f);
            }
            float4 o[4] = {{0,0,0,0},{0,0,0,0},{0,0,0,0},{0,0,0,0}};
#pragma unroll
            for (int k = 0; k < 32; ++k) {
                float hk = h[k];
#pragma unroll
                for (int qq = 0; qq < 4; ++qq) o[qq] = f4fma(hk, sW2[k * 4 + qq], o[qq]);
            }
#pragma unroll
            for (int qq = 0; qq < 4; ++qq) {
                o[qq].x *= di; o[qq].y *= di; o[qq].z *= di; o[qq].w *= di;
                h2n[(size_t)ii * 4 + qq] = o[qq];
            }
        }
    }
}

// layer 2: 4-way CHANNEL-split gather of h2n (16ch) + relu + 16->8, write h3n*dinv
__global__ __launch_bounds__(256) void g2(const int* __restrict__ rowptr,
                                          const int* __restrict__ rowend,
                                          const int* __restrict__ srcs,
                                          const float4* __restrict__ h2n,
                                          const float* __restrict__ dinv,
                                          const float* __restrict__ b2,
                                          const float* __restrict__ W3,
                                          float4* __restrict__ h3n) {
    __shared__ float4 sAcc[NPB][4];
    __shared__ float4 sW3[32];    // [16][8] as 16 rows x 2 quads
    int t = threadIdx.x;
    if (t < 32) sW3[t] = ((const float4*)W3)[t];
    int nl = t >> 2, q = t & 3;
    int i = blockIdx.x * NPB + nl;
    float4 acc = {0, 0, 0, 0};
    if (i < N_NODES) {
        acc = h2n[(size_t)i * 4 + q];         // self loop
        int r0 = rowptr[i], r1 = rowend[i];
        for (int j = r0; j < r1; ++j) {
            float4 v = h2n[(size_t)srcs[j] * 4 + q];
            acc.x += v.x; acc.y += v.y; acc.z += v.z; acc.w += v.w;
        }
    }
    sAcc[nl][q] = acc;
    __syncthreads();
    if (t < NPB) {
        int ii = blockIdx.x * NPB + t;
        if (ii < N_NODES) {
            float di = dinv[ii];
            float act[16];
#pragma unroll
            for (int qq = 0; qq < 4; ++qq) {
                float4 a = sAcc[t][qq];
                act[4 * qq]     = fmaxf(fmaf(di, a.x, b2[4 * qq]), 0.0f);
                act[4 * qq + 1] = fmaxf(fmaf(di, a.y, b2[4 * qq + 1]), 0.0f);
                act[4 * qq + 2] = fmaxf(fmaf(di, a.z, b2[4 * qq + 2]), 0.0f);
                act[4 * qq + 3] = fmaxf(fmaf(di, a.w, b2[4 * qq + 3]), 0.0f);
            }
            float4 o0 = {0,0,0,0}, o1 = {0,0,0,0};
#pragma unroll
            for (int k = 0; k < 16; ++k) {
                o0 = f4fma(act[k], sW3[k * 2], o0);
                o1 = f4fma(act[k], sW3[k * 2 + 1], o1);
            }
            o0.x *= di; o0.y *= di; o0.z *= di; o0.w *= di;
            o1.x *= di; o1.y *= di; o1.z *= di; o1.w *= di;
            h3n[(size_t)ii * 2]     = o0;
            h3n[(size_t)ii * 2 + 1] = o1;
        }
    }
}

// layer 3: 2x2 (channel x edge-parity) split gather of h3n (8ch) + relu + 8->1, write out
__global__ __launch_bounds__(256) void g3(const int* __restrict__ rowptr,
                                          const int* __restrict__ rowend,
                                          const int* __restrict__ srcs,
                                          const float4* __restrict__ h3n,
                                          const float* __restrict__ dinv,
                                          const float* __restrict__ b3,
                                          const float* __restrict__ Wf,
                                          const float* __restrict__ bf,
                                          float* __restrict__ out) {
    __shared__ float4 sAcc[NPB][4];
    int t = threadIdx.x;
    int nl = t >> 2, q = t & 1, half = (t >> 1) & 1;
    int i = blockIdx.x * NPB + nl;
    float4 acc = {0, 0, 0, 0};
    if (i < N_NODES) {
        if (half == 0) acc = h3n[(size_t)i * 2 + q];   // self loop
        int r0 = rowptr[i], r1 = rowend[i];
        for (int j = r0 + half; j < r1; j += 2) {
            float4 v = h3n[(size_t)srcs[j] * 2 + q];
            acc.x += v.x; acc.y += v.y; acc.z += v.z; acc.w += v.w;
        }
    }
    sAcc[nl][(half << 1) | q] = acc;
    __syncthreads();
    if (t < NPB) {
        int ii = blockIdx.x * NPB + t;
        if (ii < N_NODES) {
            float4 a0 = sAcc[t][0], a1 = sAcc[t][1], a2 = sAcc[t][2], a3 = sAcc[t][3];
            a0.x += a2.x; a0.y += a2.y; a0.z += a2.z; a0.w += a2.w;   // quad 0
            a1.x += a3.x; a1.y += a3.y; a1.z += a3.z; a1.w += a3.w;   // quad 1
            float di = dinv[ii];
            float s = bf[0];
            s = fmaf(fmaxf(fmaf(di, a0.x, b3[0]), 0.0f), Wf[0], s);
            s = fmaf(fmaxf(fmaf(di, a0.y, b3[1]), 0.0f), Wf[1], s);
            s = fmaf(fmaxf(fmaf(di, a0.z, b3[2]), 0.0f), Wf[2], s);
            s = fmaf(fmaxf(fmaf(di, a0.w, b3[3]), 0.0f), Wf[3], s);
            s = fmaf(fmaxf(fmaf(di, a1.x, b3[4]), 0.0f), Wf[4], s);
            s = fmaf(fmaxf(fmaf(di, a1.y, b3[5]), 0.0f), Wf[5], s);
            s = fmaf(fmaxf(fmaf(di, a1.z, b3[6]), 0.0f), Wf[6], s);
            s = fmaf(fmaxf(fmaf(di, a1.w, b3[7]), 0.0f), Wf[7], s);
            out[ii] = s;
        }
    }
}

// ---------------- launch ----------------

extern "C" void kernel_launch(void* const* d_in, const int* in_sizes, int n_in,
                              void* d_out, int out_size, void* d_ws, size_t ws_size,
                              hipStream_t stream) {
    const float* x  = (const float*)d_in[0];
    const int*   ei = (const int*)d_in[1];
    const float* W1 = (const float*)d_in[2];
    const float* b1 = (const float*)d_in[3];
    const float* W2 = (const float*)d_in[4];
    const float* b2 = (const float*)d_in[5];
    const float* W3 = (const float*)d_in[6];
    const float* b3 = (const float*)d_in[7];
    const float* Wf = (const float*)d_in[8];
    const float* bf = (const float*)d_in[9];
    float* out = (float*)d_out;

    const int n = N_NODES;
    const int e = N_EDGES;
    const int* src = ei;
    const int* dst = ei + e;

    // workspace: xd[n]f4 | h2n[n*4]f4 | h3n[n*2]f4 | dinv[n] |
    //            srcs[NREG*CAP] | staging[NREG*CAP] | rowptr[n] | rowend[n] | regionCursor[NREG]
    float4*   xd   = (float4*)d_ws;
    float4*   h2n  = xd + n;
    float4*   h3n  = h2n + (size_t)n * 4;
    float*    dinv = (float*)(h3n + (size_t)n * 2);
    int*      srcs    = (int*)(dinv + n);
    unsigned* staging = (unsigned*)(srcs + (size_t)NREG * CAP);
    int*      rowptr  = (int*)(staging + (size_t)NREG * CAP);
    int*      rowend  = rowptr + n;
    int*      regionCursor = rowend + n;

    // ---- CSR build (single-pass radix partition) ----
    k_zero_cur<<<1, 256, 0, stream>>>(regionCursor);
    k_place<<<NWG_E, 256, 0, stream>>>(src, dst, regionCursor, staging);
    k_build<<<NREG, 512, 0, stream>>>(staging, regionCursor, x, rowptr, rowend, dinv, xd, srcs);

    // ---- fused layers (4 threads/node) ----
    const int gBlocks = cdiv(n, NPB);   // 1563
    g1<<<gBlocks, 256, 0, stream>>>(rowptr, rowend, srcs, xd, dinv, b1, W1, W2, h2n);
    g2<<<gBlocks, 256, 0, stream>>>(rowptr, rowend, srcs, h2n, dinv, b2, W3, h3n);
    g3<<<gBlocks, 256, 0, stream>>>(rowptr, rowend, srcs, h3n, dinv, b3, Wf, bf, out);
}

// Round 11
// 107.379 us; speedup vs baseline: 3.2098x; 1.0225x over previous
//
#include <hip/hip_runtime.h>

#define N_NODES 100000
#define N_EDGES 1600000
#define RSHIFT 9
#define RSIZE 512
#define NREG 196            // cdiv(100000, 512)
#define CAP 16384           // staging slots per region (expected 8192, sd ~90)
#define CH 2048             // edges per workgroup in place pass
#define EPT 8               // edges per thread in place pass (CH/256)
#define NWG_E 782           // cdiv(N_EDGES, CH)
#define NPB 32              // nodes per block in gather kernels (8 threads/node)

static inline int cdiv(int a, int b) { return (a + b - 1) / b; }

__device__ inline float4 f4fma(float s, float4 w, float4 a) {
    a.x = fmaf(s, w.x, a.x); a.y = fmaf(s, w.y, a.y);
    a.z = fmaf(s, w.z, a.z); a.w = fmaf(s, w.w, a.w); return a;
}

// ---------------- CSR build: single-pass place + per-region build ----------------

__global__ void k_zero_cur(int* __restrict__ p) {
    int i = threadIdx.x;
    if (i < NREG) p[i] = 0;
}

// LDS hist -> reserve -> place, with the 8 packed words kept in registers (no re-read)
__global__ __launch_bounds__(256) void k_place(const int* __restrict__ src,
                                               const int* __restrict__ dst,
                                               int* __restrict__ regionCursor,
                                               unsigned* __restrict__ staging) {
    __shared__ int h[NREG];
    __shared__ int cur[NREG];
    int wg = blockIdx.x;
    int t = threadIdx.x;
    for (int u = t; u < NREG; u += 256) h[u] = 0;
    __syncthreads();
    int e0 = wg * CH;
    int e1 = e0 + CH; if (e1 > N_EDGES) e1 = N_EDGES;

    unsigned pk[EPT];
    int      rg[EPT];
    int myBase = e0 + t * EPT;
    bool active = myBase < e1;     // chunk sizes are multiples of 8
    if (active) {
        const int4* s4 = (const int4*)src;
        const int4* d4 = (const int4*)dst;
        int b4 = myBase >> 2;
#pragma unroll
        for (int u = 0; u < 2; ++u) {
            int4 s = s4[b4 + u];
            int4 d = d4[b4 + u];
            pk[4 * u]     = ((unsigned)(d.x & (RSIZE - 1)) << 17) | (unsigned)s.x;
            pk[4 * u + 1] = ((unsigned)(d.y & (RSIZE - 1)) << 17) | (unsigned)s.y;
            pk[4 * u + 2] = ((unsigned)(d.z & (RSIZE - 1)) << 17) | (unsigned)s.z;
            pk[4 * u + 3] = ((unsigned)(d.w & (RSIZE - 1)) << 17) | (unsigned)s.w;
            rg[4 * u]     = d.x >> RSHIFT;
            rg[4 * u + 1] = d.y >> RSHIFT;
            rg[4 * u + 2] = d.z >> RSHIFT;
            rg[4 * u + 3] = d.w >> RSHIFT;
        }
#pragma unroll
        for (int u = 0; u < EPT; ++u) atomicAdd(&h[rg[u]], 1);
    }
    __syncthreads();
    for (int u = t; u < NREG; u += 256)
        cur[u] = u * CAP + atomicAdd(&regionCursor[u], h[u]);
    __syncthreads();
    if (active) {
#pragma unroll
        for (int u = 0; u < EPT; ++u) {
            int p = atomicAdd(&cur[rg[u]], 1);
            staging[p] = pk[u];
        }
    }
}

__global__ __launch_bounds__(512) void k_build(const unsigned* __restrict__ staging,
                                               const int* __restrict__ regionCursor,
                                               const float* __restrict__ x,
                                               int* __restrict__ rowptr,
                                               int* __restrict__ rowend,
                                               float* __restrict__ dinv,
                                               float4* __restrict__ xd,
                                               int* __restrict__ srcs) {
    __shared__ int cnt[RSIZE];
    __shared__ int scn[RSIZE];
    int r = blockIdx.x;
    int t = threadIdx.x;
    int base = r << RSHIFT;
    int nloc = N_NODES - base; if (nloc > RSIZE) nloc = RSIZE;
    int e0 = r * CAP;
    int e1 = e0 + regionCursor[r];
    cnt[t] = 0;
    __syncthreads();
    for (int k = e0 + t; k < e1; k += 512) atomicAdd(&cnt[staging[k] >> 17], 1);
    __syncthreads();
    int v = cnt[t];
    scn[t] = v;
    __syncthreads();
    for (int off = 1; off < RSIZE; off <<= 1) {
        int y = (t >= off) ? scn[t - off] : 0;
        __syncthreads();
        scn[t] += y;
        __syncthreads();
    }
    int excl = scn[t] - v;
    if (t < nloc) {
        int i = base + t;
        rowptr[i] = e0 + excl;
        rowend[i] = e0 + excl + v;
        float di = rsqrtf((float)(v + 1));
        dinv[i] = di;
        float4 vv;
        vv.x = x[3 * i] * di; vv.y = x[3 * i + 1] * di; vv.z = x[3 * i + 2] * di; vv.w = 0.0f;
        xd[i] = vv;
    }
    cnt[t] = e0 + excl;   // reuse as cursor
    __syncthreads();
    for (int k = e0 + t; k < e1; k += 512) {
        unsigned p = staging[k];
        int pos = atomicAdd(&cnt[p >> 17], 1);
        srcs[pos] = (int)(p & 0x1FFFFu);
    }
}

// ---------------- fused layers: 8 threads/node gather + LDS exchange ----------------

// layer 1: 8-way EDGE-split aggregate of xd + 3->32 relu + 32->16, write h2n*dinv
__global__ __launch_bounds__(256) void g1(const int* __restrict__ rowptr,
                                          const int* __restrict__ rowend,
                                          const int* __restrict__ srcs,
                                          const float4* __restrict__ xd,
                                          const float* __restrict__ dinv,
                                          const float* __restrict__ b1,
                                          const float* __restrict__ W1,
                                          const float* __restrict__ W2,
                                          float4* __restrict__ h2n) {
    __shared__ float4 sAcc[NPB][8];
    __shared__ float4 sW1[24];    // [3][32] as 3 rows x 8 quads
    __shared__ float4 sW2[128];   // [32][16] as 32 rows x 4 quads
    int t = threadIdx.x;
    if (t < 24) sW1[t] = ((const float4*)W1)[t];
    if (t >= 24 && t < 152) sW2[t - 24] = ((const float4*)W2)[t - 24];
    int nl = t >> 3, q = t & 7;
    int i = blockIdx.x * NPB + nl;
    float4 acc = {0, 0, 0, 0};
    if (i < N_NODES) {
        if (q == 0) acc = xd[i];              // self loop
        int r0 = rowptr[i], r1 = rowend[i];
        for (int j = r0 + q; j < r1; j += 8) {
            float4 v = xd[srcs[j]];
            acc.x += v.x; acc.y += v.y; acc.z += v.z;
        }
    }
    sAcc[nl][q] = acc;
    __syncthreads();
    if (t < NPB) {
        int ii = blockIdx.x * NPB + t;
        if (ii < N_NODES) {
            float ax = 0.0f, ay = 0.0f, az = 0.0f;
#pragma unroll
            for (int u = 0; u < 8; ++u) {
                float4 p = sAcc[t][u];
                ax += p.x; ay += p.y; az += p.z;
            }
            float di = dinv[ii];
            const float4* b14 = (const float4*)b1;
            float h[32];
#pragma unroll
            for (int qq = 0; qq < 8; ++qq) {
                float4 s = {0, 0, 0, 0};
                s = f4fma(ax, sW1[qq], s);
                s = f4fma(ay, sW1[8 + qq], s);
                s = f4fma(az, sW1[16 + qq], s);
                float4 bb = b14[qq];
                h[4 * qq]     = fmaxf(fmaf(di, s.x, bb.x), 0.0f);
                h[4 * qq + 1] = fmaxf(fmaf(di, s.y, bb.y), 0.0f);
                h[4 * qq + 2] = fmaxf(fmaf(di, s.z, bb.z), 0.0f);
                h[4 * qq + 3] = fmaxf(fmaf(di, s.w, bb.w), 0.0f);
            }
            float4 o[4] = {{0,0,0,0},{0,0,0,0},{0,0,0,0},{0,0,0,0}};
#pragma unroll
            for (int k = 0; k < 32; ++k) {
                float hk = h[k];
#pragma unroll
                for (int qq = 0; qq < 4; ++qq) o[qq] = f4fma(hk, sW2[k * 4 + qq], o[qq]);
            }
#pragma unroll
            for (int qq = 0; qq < 4; ++qq) {
                o[qq].x *= di; o[qq].y *= di; o[qq].z *= di; o[qq].w *= di;
                h2n[(size_t)ii * 4 + qq] = o[qq];
            }
        }
    }
}

// layer 2: 4-way CHANNEL x 2-way EDGE split gather of h2n (16ch) + relu + 16->8
__global__ __launch_bounds__(256) void g2(const int* __restrict__ rowptr,
                                          const int* __restrict__ rowend,
                                          const int* __restrict__ srcs,
                                          const float4* __restrict__ h2n,
                                          const float* __restrict__ dinv,
                                          const float* __restrict__ b2,
                                          const float* __restrict__ W3,
                                          float4* __restrict__ h3n) {
    __shared__ float4 sAcc[NPB][8];
    __shared__ float4 sW3[32];    // [16][8] as 16 rows x 2 quads
    int t = threadIdx.x;
    if (t < 32) sW3[t] = ((const float4*)W3)[t];
    int nl = t >> 3, q = t & 3, half = (t >> 2) & 1;
    int i = blockIdx.x * NPB + nl;
    float4 acc = {0, 0, 0, 0};
    if (i < N_NODES) {
        if (half == 0) acc = h2n[(size_t)i * 4 + q];   // self loop
        int r0 = rowptr[i], r1 = rowend[i];
        for (int j = r0 + half; j < r1; j += 2) {
            float4 v = h2n[(size_t)srcs[j] * 4 + q];
            acc.x += v.x; acc.y += v.y; acc.z += v.z; acc.w += v.w;
        }
    }
    sAcc[nl][(half << 2) | q] = acc;
    __syncthreads();
    if (t < NPB) {
        int ii = blockIdx.x * NPB + t;
        if (ii < N_NODES) {
            float di = dinv[ii];
            float act[16];
#pragma unroll
            for (int qq = 0; qq < 4; ++qq) {
                float4 a = sAcc[t][qq];
                float4 b = sAcc[t][4 + qq];
                a.x += b.x; a.y += b.y; a.z += b.z; a.w += b.w;
                act[4 * qq]     = fmaxf(fmaf(di, a.x, b2[4 * qq]), 0.0f);
                act[4 * qq + 1] = fmaxf(fmaf(di, a.y, b2[4 * qq + 1]), 0.0f);
                act[4 * qq + 2] = fmaxf(fmaf(di, a.z, b2[4 * qq + 2]), 0.0f);
                act[4 * qq + 3] = fmaxf(fmaf(di, a.w, b2[4 * qq + 3]), 0.0f);
            }
            float4 o0 = {0,0,0,0}, o1 = {0,0,0,0};
#pragma unroll
            for (int k = 0; k < 16; ++k) {
                o0 = f4fma(act[k], sW3[k * 2], o0);
                o1 = f4fma(act[k], sW3[k * 2 + 1], o1);
            }
            o0.x *= di; o0.y *= di; o0.z *= di; o0.w *= di;
            o1.x *= di; o1.y *= di; o1.z *= di; o1.w *= di;
            h3n[(size_t)ii * 2]     = o0;
            h3n[(size_t)ii * 2 + 1] = o1;
        }
    }
}

// layer 3: 2-way CHANNEL x 4-way EDGE split gather of h3n (8ch) + relu + 8->1
__global__ __launch_bounds__(256) void g3(const int* __restrict__ rowptr,
                                          const int* __restrict__ rowend,
                                          const int* __restrict__ srcs,
                                          const float4* __restrict__ h3n,
                                          const float* __restrict__ dinv,
                                          const float* __restrict__ b3,
                                          const float* __restrict__ Wf,
                                          const float* __restrict__ bf,
                                          float* __restrict__ out) {
    __shared__ float4 sAcc[NPB][8];
    int t = threadIdx.x;
    int nl = t >> 3, q = t & 1, half = (t >> 1) & 3;
    int i = blockIdx.x * NPB + nl;
    float4 acc = {0, 0, 0, 0};
    if (i < N_NODES) {
        if (half == 0) acc = h3n[(size_t)i * 2 + q];   // self loop
        int r0 = rowptr[i], r1 = rowend[i];
        for (int j = r0 + half; j < r1; j += 4) {
            float4 v = h3n[(size_t)srcs[j] * 2 + q];
            acc.x += v.x; acc.y += v.y; acc.z += v.z; acc.w += v.w;
        }
    }
    sAcc[nl][(half << 1) | q] = acc;
    __syncthreads();
    if (t < NPB) {
        int ii = blockIdx.x * NPB + t;
        if (ii < N_NODES) {
            float4 a0 = sAcc[t][0], a1 = sAcc[t][1];
#pragma unroll
            for (int hh = 1; hh < 4; ++hh) {
                float4 c0 = sAcc[t][(hh << 1)];
                float4 c1 = sAcc[t][(hh << 1) | 1];
                a0.x += c0.x; a0.y += c0.y; a0.z += c0.z; a0.w += c0.w;
                a1.x += c1.x; a1.y += c1.y; a1.z += c1.z; a1.w += c1.w;
            }
            float di = dinv[ii];
            float s = bf[0];
            s = fmaf(fmaxf(fmaf(di, a0.x, b3[0]), 0.0f), Wf[0], s);
            s = fmaf(fmaxf(fmaf(di, a0.y, b3[1]), 0.0f), Wf[1], s);
            s = fmaf(fmaxf(fmaf(di, a0.z, b3[2]), 0.0f), Wf[2], s);
            s = fmaf(fmaxf(fmaf(di, a0.w, b3[3]), 0.0f), Wf[3], s);
            s = fmaf(fmaxf(fmaf(di, a1.x, b3[4]), 0.0f), Wf[4], s);
            s = fmaf(fmaxf(fmaf(di, a1.y, b3[5]), 0.0f), Wf[5], s);
            s = fmaf(fmaxf(fmaf(di, a1.z, b3[6]), 0.0f), Wf[6], s);
            s = fmaf(fmaxf(fmaf(di, a1.w, b3[7]), 0.0f), Wf[7], s);
            out[ii] = s;
        }
    }
}

// ---------------- launch ----------------

extern "C" void kernel_launch(void* const* d_in, const int* in_sizes, int n_in,
                              void* d_out, int out_size, void* d_ws, size_t ws_size,
                              hipStream_t stream) {
    const float* x  = (const float*)d_in[0];
    const int*   ei = (const int*)d_in[1];
    const float* W1 = (const float*)d_in[2];
    const float* b1 = (const float*)d_in[3];
    const float* W2 = (const float*)d_in[4];
    const float* b2 = (const float*)d_in[5];
    const float* W3 = (const float*)d_in[6];
    const float* b3 = (const float*)d_in[7];
    const float* Wf = (const float*)d_in[8];
    const float* bf = (const float*)d_in[9];
    float* out = (float*)d_out;

    const int n = N_NODES;
    const int e = N_EDGES;
    const int* src = ei;
    const int* dst = ei + e;

    // workspace: xd[n]f4 | h2n[n*4]f4 | h3n[n*2]f4 | dinv[n] |
    //            srcs[NREG*CAP] | staging[NREG*CAP] | rowptr[n] | rowend[n] | regionCursor[NREG]
    float4*   xd   = (float4*)d_ws;
    float4*   h2n  = xd + n;
    float4*   h3n  = h2n + (size_t)n * 4;
    float*    dinv = (float*)(h3n + (size_t)n * 2);
    int*      srcs    = (int*)(dinv + n);
    unsigned* staging = (unsigned*)(srcs + (size_t)NREG * CAP);
    int*      rowptr  = (int*)(staging + (size_t)NREG * CAP);
    int*      rowend  = rowptr + n;
    int*      regionCursor = rowend + n;

    // ---- CSR build (single-pass radix partition) ----
    k_zero_cur<<<1, 256, 0, stream>>>(regionCursor);
    k_place<<<NWG_E, 256, 0, stream>>>(src, dst, regionCursor, staging);
    k_build<<<NREG, 512, 0, stream>>>(staging, regionCursor, x, rowptr, rowend, dinv, xd, srcs);

    // ---- fused layers (8 threads/node) ----
    const int gBlocks = cdiv(n, NPB);   // 3125
    g1<<<gBlocks, 256, 0, stream>>>(rowptr, rowend, srcs, xd, dinv, b1, W1, W2, h2n);
    g2<<<gBlocks, 256, 0, stream>>>(rowptr, rowend, srcs, h2n, dinv, b2, W3, h3n);
    g3<<<gBlocks, 256, 0, stream>>>(rowptr, rowend, srcs, h3n, dinv, b3, Wf, bf, out);
}

// Round 12
// 98.546 us; speedup vs baseline: 3.4975x; 1.0896x over previous
//
#include <hip/hip_runtime.h>

#define N_NODES 100000
#define N_EDGES 1600000
#define RSHIFT 9
#define RSIZE 512
#define NREG 196            // cdiv(100000, 512)
#define CAP 16384           // staging slots per region (expected 8192, sd ~90)
#define CH 4096             // edges per workgroup in place pass
#define EPT 16              // edges per thread in place pass (CH/256)
#define NWG_E 391           // cdiv(N_EDGES, CH)
#define NPB 32              // nodes per block in gather kernels (8 threads/node)

static inline int cdiv(int a, int b) { return (a + b - 1) / b; }

__device__ inline float4 f4fma(float s, float4 w, float4 a) {
    a.x = fmaf(s, w.x, a.x); a.y = fmaf(s, w.y, a.y);
    a.z = fmaf(s, w.z, a.z); a.w = fmaf(s, w.w, a.w); return a;
}

// ---------------- CSR build: single-pass place + per-region build ----------------

// LDS hist -> reserve -> place, packed words kept in registers (no re-read)
__global__ __launch_bounds__(256) void k_place(const int* __restrict__ src,
                                               const int* __restrict__ dst,
                                               int* __restrict__ regionCursor,
                                               unsigned* __restrict__ staging) {
    __shared__ int h[NREG];
    __shared__ int cur[NREG];
    int wg = blockIdx.x;
    int t = threadIdx.x;
    for (int u = t; u < NREG; u += 256) h[u] = 0;
    __syncthreads();
    int e0 = wg * CH;
    int e1 = e0 + CH; if (e1 > N_EDGES) e1 = N_EDGES;

    unsigned pk[EPT];
    int      rg[EPT];
    int myBase = e0 + t * EPT;
    bool active = myBase < e1;     // chunk sizes are multiples of 16
    if (active) {
        const int4* s4 = (const int4*)src;
        const int4* d4 = (const int4*)dst;
        int b4 = myBase >> 2;
#pragma unroll
        for (int u = 0; u < EPT / 4; ++u) {
            int4 s = s4[b4 + u];
            int4 d = d4[b4 + u];
            pk[4 * u]     = ((unsigned)(d.x & (RSIZE - 1)) << 17) | (unsigned)s.x;
            pk[4 * u + 1] = ((unsigned)(d.y & (RSIZE - 1)) << 17) | (unsigned)s.y;
            pk[4 * u + 2] = ((unsigned)(d.z & (RSIZE - 1)) << 17) | (unsigned)s.z;
            pk[4 * u + 3] = ((unsigned)(d.w & (RSIZE - 1)) << 17) | (unsigned)s.w;
            rg[4 * u]     = d.x >> RSHIFT;
            rg[4 * u + 1] = d.y >> RSHIFT;
            rg[4 * u + 2] = d.z >> RSHIFT;
            rg[4 * u + 3] = d.w >> RSHIFT;
        }
#pragma unroll
        for (int u = 0; u < EPT; ++u) atomicAdd(&h[rg[u]], 1);
    }
    __syncthreads();
    for (int u = t; u < NREG; u += 256)
        cur[u] = u * CAP + atomicAdd(&regionCursor[u], h[u]);
    __syncthreads();
    if (active) {
#pragma unroll
        for (int u = 0; u < EPT; ++u) {
            int p = atomicAdd(&cur[rg[u]], 1);
            staging[p] = pk[u];
        }
    }
}

__global__ __launch_bounds__(512) void k_build(const unsigned* __restrict__ staging,
                                               const int* __restrict__ regionCursor,
                                               const float* __restrict__ x,
                                               int* __restrict__ rowptr,
                                               int* __restrict__ rowend,
                                               float* __restrict__ dinv,
                                               float4* __restrict__ xd,
                                               int* __restrict__ srcs) {
    __shared__ int cnt[RSIZE];
    __shared__ int wsum[8];
    int r = blockIdx.x;
    int t = threadIdx.x;
    int base = r << RSHIFT;
    int nloc = N_NODES - base; if (nloc > RSIZE) nloc = RSIZE;
    int e0 = r * CAP;
    int e1 = e0 + regionCursor[r];
    cnt[t] = 0;
    __syncthreads();
    for (int k = e0 + t; k < e1; k += 512) atomicAdd(&cnt[staging[k] >> 17], 1);
    __syncthreads();
    int v = cnt[t];
    // wave-level inclusive scan (64 lanes), then cross-wave offsets
    int lane = t & 63, w = t >> 6;
    int sc = v;
#pragma unroll
    for (int off = 1; off < 64; off <<= 1) {
        int y = __shfl_up(sc, off, 64);
        if (lane >= off) sc += y;
    }
    if (lane == 63) wsum[w] = sc;
    __syncthreads();
    if (t < 64) {
        int y = (lane < 8) ? wsum[lane] : 0;
#pragma unroll
        for (int off = 1; off < 8; off <<= 1) {
            int z = __shfl_up(y, off, 64);
            if (lane >= off) y += z;
        }
        if (lane < 8) wsum[lane] = y;   // inclusive wave totals
    }
    __syncthreads();
    int wbase = (w > 0) ? wsum[w - 1] : 0;
    int excl = wbase + sc - v;
    if (t < nloc) {
        int i = base + t;
        rowptr[i] = e0 + excl;
        rowend[i] = e0 + excl + v;
        float di = rsqrtf((float)(v + 1));
        dinv[i] = di;
        float4 vv;
        vv.x = x[3 * i] * di; vv.y = x[3 * i + 1] * di; vv.z = x[3 * i + 2] * di; vv.w = 0.0f;
        xd[i] = vv;
    }
    cnt[t] = e0 + excl;   // reuse as cursor
    __syncthreads();
    for (int k = e0 + t; k < e1; k += 512) {
        unsigned p = staging[k];
        int pos = atomicAdd(&cnt[p >> 17], 1);
        srcs[pos] = (int)(p & 0x1FFFFu);
    }
}

// ---------------- fused layers: 8 threads/node gather + LDS exchange ----------------

// layer 1: 8-way EDGE-split aggregate of xd + 3->32 relu + 32->16, write h2n*dinv
__global__ __launch_bounds__(256) void g1(const int* __restrict__ rowptr,
                                          const int* __restrict__ rowend,
                                          const int* __restrict__ srcs,
                                          const float4* __restrict__ xd,
                                          const float* __restrict__ dinv,
                                          const float* __restrict__ b1,
                                          const float* __restrict__ W1,
                                          const float* __restrict__ W2,
                                          float4* __restrict__ h2n) {
    __shared__ float4 sAcc[NPB][8];
    __shared__ float4 sW1[24];    // [3][32] as 3 rows x 8 quads
    __shared__ float4 sW2[128];   // [32][16] as 32 rows x 4 quads
    int t = threadIdx.x;
    if (t < 24) sW1[t] = ((const float4*)W1)[t];
    if (t >= 24 && t < 152) sW2[t - 24] = ((const float4*)W2)[t - 24];
    int nl = t >> 3, q = t & 7;
    int i = blockIdx.x * NPB + nl;
    float4 acc = {0, 0, 0, 0};
    if (i < N_NODES) {
        if (q == 0) acc = xd[i];              // self loop
        int r0 = rowptr[i], r1 = rowend[i];
        int j = r0 + q;
        int s = (j < r1) ? srcs[j] : 0;
        for (; j < r1; j += 8) {
            int jn = j + 8;
            int sn = (jn < r1) ? srcs[jn] : 0;   // prefetch next index
            float4 v = xd[s];
            acc.x += v.x; acc.y += v.y; acc.z += v.z;
            s = sn;
        }
    }
    sAcc[nl][q] = acc;
    __syncthreads();
    if (t < NPB) {
        int ii = blockIdx.x * NPB + t;
        if (ii < N_NODES) {
            float ax = 0.0f, ay = 0.0f, az = 0.0f;
#pragma unroll
            for (int u = 0; u < 8; ++u) {
                float4 p = sAcc[t][u];
                ax += p.x; ay += p.y; az += p.z;
            }
            float di = dinv[ii];
            const float4* b14 = (const float4*)b1;
            float h[32];
#pragma unroll
            for (int qq = 0; qq < 8; ++qq) {
                float4 s = {0, 0, 0, 0};
                s = f4fma(ax, sW1[qq], s);
                s = f4fma(ay, sW1[8 + qq], s);
                s = f4fma(az, sW1[16 + qq], s);
                float4 bb = b14[qq];
                h[4 * qq]     = fmaxf(fmaf(di, s.x, bb.x), 0.0f);
                h[4 * qq + 1] = fmaxf(fmaf(di, s.y, bb.y), 0.0f);
                h[4 * qq + 2] = fmaxf(fmaf(di, s.z, bb.z), 0.0f);
                h[4 * qq + 3] = fmaxf(fmaf(di, s.w, bb.w), 0.0f);
            }
            float4 o[4] = {{0,0,0,0},{0,0,0,0},{0,0,0,0},{0,0,0,0}};
#pragma unroll
            for (int k = 0; k < 32; ++k) {
                float hk = h[k];
#pragma unroll
                for (int qq = 0; qq < 4; ++qq) o[qq] = f4fma(hk, sW2[k * 4 + qq], o[qq]);
            }
#pragma unroll
            for (int qq = 0; qq < 4; ++qq) {
                o[qq].x *= di; o[qq].y *= di; o[qq].z *= di; o[qq].w *= di;
                h2n[(size_t)ii * 4 + qq] = o[qq];
            }
        }
    }
}

// layer 2: 4-way CHANNEL x 2-way EDGE split gather of h2n (16ch) + relu + 16->8
__global__ __launch_bounds__(256) void g2(const int* __restrict__ rowptr,
                                          const int* __restrict__ rowend,
                                          const int* __restrict__ srcs,
                                          const float4* __restrict__ h2n,
                                          const float* __restrict__ dinv,
                                          const float* __restrict__ b2,
                                          const float* __restrict__ W3,
                                          float4* __restrict__ h3n) {
    __shared__ float4 sAcc[NPB][8];
    __shared__ float4 sW3[32];    // [16][8] as 16 rows x 2 quads
    int t = threadIdx.x;
    if (t < 32) sW3[t] = ((const float4*)W3)[t];
    int nl = t >> 3, q = t & 3, half = (t >> 2) & 1;
    int i = blockIdx.x * NPB + nl;
    float4 acc = {0, 0, 0, 0};
    if (i < N_NODES) {
        if (half == 0) acc = h2n[(size_t)i * 4 + q];   // self loop
        int r0 = rowptr[i], r1 = rowend[i];
        int j = r0 + half;
        int s = (j < r1) ? srcs[j] : 0;
        for (; j < r1; j += 2) {
            int jn = j + 2;
            int sn = (jn < r1) ? srcs[jn] : 0;
            float4 v = h2n[(size_t)s * 4 + q];
            acc.x += v.x; acc.y += v.y; acc.z += v.z; acc.w += v.w;
            s = sn;
        }
    }
    sAcc[nl][(half << 2) | q] = acc;
    __syncthreads();
    if (t < NPB) {
        int ii = blockIdx.x * NPB + t;
        if (ii < N_NODES) {
            float di = dinv[ii];
            float act[16];
#pragma unroll
            for (int qq = 0; qq < 4; ++qq) {
                float4 a = sAcc[t][qq];
                float4 b = sAcc[t][4 + qq];
                a.x += b.x; a.y += b.y; a.z += b.z; a.w += b.w;
                act[4 * qq]     = fmaxf(fmaf(di, a.x, b2[4 * qq]), 0.0f);
                act[4 * qq + 1] = fmaxf(fmaf(di, a.y, b2[4 * qq + 1]), 0.0f);
                act[4 * qq + 2] = fmaxf(fmaf(di, a.z, b2[4 * qq + 2]), 0.0f);
                act[4 * qq + 3] = fmaxf(fmaf(di, a.w, b2[4 * qq + 3]), 0.0f);
            }
            float4 o0 = {0,0,0,0}, o1 = {0,0,0,0};
#pragma unroll
            for (int k = 0; k < 16; ++k) {
                o0 = f4fma(act[k], sW3[k * 2], o0);
                o1 = f4fma(act[k], sW3[k * 2 + 1], o1);
            }
            o0.x *= di; o0.y *= di; o0.z *= di; o0.w *= di;
            o1.x *= di; o1.y *= di; o1.z *= di; o1.w *= di;
            h3n[(size_t)ii * 2]     = o0;
            h3n[(size_t)ii * 2 + 1] = o1;
        }
    }
}

// layer 3: 2-way CHANNEL x 4-way EDGE split gather of h3n (8ch) + relu + 8->1
__global__ __launch_bounds__(256) void g3(const int* __restrict__ rowptr,
                                          const int* __restrict__ rowend,
                                          const int* __restrict__ srcs,
                                          const float4* __restrict__ h3n,
                                          const float* __restrict__ dinv,
                                          const float* __restrict__ b3,
                                          const float* __restrict__ Wf,
                                          const float* __restrict__ bf,
                                          float* __restrict__ out) {
    __shared__ float4 sAcc[NPB][8];
    int t = threadIdx.x;
    int nl = t >> 3, q = t & 1, half = (t >> 1) & 3;
    int i = blockIdx.x * NPB + nl;
    float4 acc = {0, 0, 0, 0};
    if (i < N_NODES) {
        if (half == 0) acc = h3n[(size_t)i * 2 + q];   // self loop
        int r0 = rowptr[i], r1 = rowend[i];
        int j = r0 + half;
        int s = (j < r1) ? srcs[j] : 0;
        for (; j < r1; j += 4) {
            int jn = j + 4;
            int sn = (jn < r1) ? srcs[jn] : 0;
            float4 v = h3n[(size_t)s * 2 + q];
            acc.x += v.x; acc.y += v.y; acc.z += v.z; acc.w += v.w;
            s = sn;
        }
    }
    sAcc[nl][(half << 1) | q] = acc;
    __syncthreads();
    if (t < NPB) {
        int ii = blockIdx.x * NPB + t;
        if (ii < N_NODES) {
            float4 a0 = sAcc[t][0], a1 = sAcc[t][1];
#pragma unroll
            for (int hh = 1; hh < 4; ++hh) {
                float4 c0 = sAcc[t][(hh << 1)];
                float4 c1 = sAcc[t][(hh << 1) | 1];
                a0.x += c0.x; a0.y += c0.y; a0.z += c0.z; a0.w += c0.w;
                a1.x += c1.x; a1.y += c1.y; a1.z += c1.z; a1.w += c1.w;
            }
            float di = dinv[ii];
            float s = bf[0];
            s = fmaf(fmaxf(fmaf(di, a0.x, b3[0]), 0.0f), Wf[0], s);
            s = fmaf(fmaxf(fmaf(di, a0.y, b3[1]), 0.0f), Wf[1], s);
            s = fmaf(fmaxf(fmaf(di, a0.z, b3[2]), 0.0f), Wf[2], s);
            s = fmaf(fmaxf(fmaf(di, a0.w, b3[3]), 0.0f), Wf[3], s);
            s = fmaf(fmaxf(fmaf(di, a1.x, b3[4]), 0.0f), Wf[4], s);
            s = fmaf(fmaxf(fmaf(di, a1.y, b3[5]), 0.0f), Wf[5], s);
            s = fmaf(fmaxf(fmaf(di, a1.z, b3[6]), 0.0f), Wf[6], s);
            s = fmaf(fmaxf(fmaf(di, a1.w, b3[7]), 0.0f), Wf[7], s);
            out[ii] = s;
        }
    }
}

// ---------------- launch ----------------

extern "C" void kernel_launch(void* const* d_in, const int* in_sizes, int n_in,
                              void* d_out, int out_size, void* d_ws, size_t ws_size,
                              hipStream_t stream) {
    const float* x  = (const float*)d_in[0];
    const int*   ei = (const int*)d_in[1];
    const float* W1 = (const float*)d_in[2];
    const float* b1 = (const float*)d_in[3];
    const float* W2 = (const float*)d_in[4];
    const float* b2 = (const float*)d_in[5];
    const float* W3 = (const float*)d_in[6];
    const float* b3 = (const float*)d_in[7];
    const float* Wf = (const float*)d_in[8];
    const float* bf = (const float*)d_in[9];
    float* out = (float*)d_out;

    const int n = N_NODES;
    const int e = N_EDGES;
    const int* src = ei;
    const int* dst = ei + e;

    // workspace: xd[n]f4 | h2n[n*4]f4 | h3n[n*2]f4 | dinv[n] |
    //            srcs[NREG*CAP] | staging[NREG*CAP] | rowptr[n] | rowend[n] | regionCursor[NREG]
    float4*   xd   = (float4*)d_ws;
    float4*   h2n  = xd + n;
    float4*   h3n  = h2n + (size_t)n * 4;
    float*    dinv = (float*)(h3n + (size_t)n * 2);
    int*      srcs    = (int*)(dinv + n);
    unsigned* staging = (unsigned*)(srcs + (size_t)NREG * CAP);
    int*      rowptr  = (int*)(staging + (size_t)NREG * CAP);
    int*      rowend  = rowptr + n;
    int*      regionCursor = rowend + n;

    // ---- CSR build (single-pass radix partition) ----
    hipMemsetAsync(regionCursor, 0, NREG * sizeof(int), stream);
    k_place<<<NWG_E, 256, 0, stream>>>(src, dst, regionCursor, staging);
    k_build<<<NREG, 512, 0, stream>>>(staging, regionCursor, x, rowptr, rowend, dinv, xd, srcs);

    // ---- fused layers (8 threads/node) ----
    const int gBlocks = cdiv(n, NPB);   // 3125
    g1<<<gBlocks, 256, 0, stream>>>(rowptr, rowend, srcs, xd, dinv, b1, W1, W2, h2n);
    g2<<<gBlocks, 256, 0, stream>>>(rowptr, rowend, srcs, h2n, dinv, b2, W3, h3n);
    g3<<<gBlocks, 256, 0, stream>>>(rowptr, rowend, srcs, h3n, dinv, b3, Wf, bf, out);
}